// Round 10
// baseline (213.537 us; speedup 1.0000x reference)
//
#include <hip/hip_runtime.h>

#define N_NODES 100000
#define N_EDGES 1600000
#define D 64
#define NBUCKET 391              // ceil(N_NODES/256), bucket = 256 dst nodes
#define QCAP_B 4800              // per-bucket queue cap (mean 4096, sd ~64)
#define EPB 4096                 // edges per sort block
#define SORT_BLOCKS 391          // ceil(N_EDGES/EPB)

typedef unsigned short u16;
typedef short bf16x8 __attribute__((ext_vector_type(8)));
typedef short s16x4  __attribute__((ext_vector_type(4)));
typedef float f32x4  __attribute__((ext_vector_type(4)));
typedef unsigned u32x4 __attribute__((ext_vector_type(4)));   // nt-load safe

__device__ __forceinline__ float bf2f(u16 u) {
    unsigned v = (unsigned)u << 16;
    float f;
    __builtin_memcpy(&f, &v, 4);
    return f;
}
__device__ __forceinline__ u16 f2bf(float f) {
    unsigned u;
    __builtin_memcpy(&u, &f, 4);
    u = (u + 0x7FFFu + ((u >> 16) & 1u)) >> 16;
    return (u16)u;
}

// ---------------------------------------------------------------------------
// Tiny prep (1 block): qtail zero (must precede sort's atomics), dummy-row
// zero, W1/W2 -> bf16 MFMA B-fragment pack.
// frag f = (layer*4 + ct)*2 + kf holds B[k=kf*32+quad*8+j][n=ct*16+(lane&15)]
// at u16 offset f*512 + lane*8 + j.
// ---------------------------------------------------------------------------
__global__ __launch_bounds__(256) void misc_kernel(
    const float* __restrict__ W1, const float* __restrict__ W2,
    u16* __restrict__ Wf, int* __restrict__ qtail, u16* __restrict__ xb)
{
    int tid = threadIdx.x;
    qtail[tid] = 0;
    qtail[tid + 256] = 0;
    if (tid < 32)
        ((unsigned*)(xb + (size_t)N_NODES * D))[tid] = 0;
#pragma unroll
    for (int t = tid; t < 16 * 64; t += 256) {
        int f = t >> 6, lane = t & 63;
        int layer = f >> 3, ct = (f >> 1) & 3, kf = f & 1;
        const float* W = layer ? W2 : W1;
        int col = ct * 16 + (lane & 15);
        int krow = kf * 32 + (lane >> 4) * 8;
        u16* o = Wf + f * 512 + lane * 8;
#pragma unroll
        for (int j = 0; j < 8; ++j)
            o[j] = f2bf(W[(krow + j) * D + col]);
    }
}

// ---------------------------------------------------------------------------
// Block-level counting sort of 4096 edges into 391 bucket queues.
// 1024 threads, wave-shfl scan, register-staged ei (each thread owns 4
// contiguous edges loaded once as two uint4), PLUS the bulk x->bf16 convert
// grid-strided across the kernel (HBM work hidden under sort latency).
// Entry packs (dst&255)<<17 | src.
// ---------------------------------------------------------------------------
__global__ __launch_bounds__(1024) void sort_kernel(
    const int* __restrict__ ei, int* __restrict__ qtail,
    unsigned* __restrict__ queue, const float* __restrict__ x,
    u16* __restrict__ xb)
{
    __shared__ int cnt[512];
    __shared__ int base_s[512];
    __shared__ int gbase[512];
    __shared__ int run[512];
    __shared__ unsigned staged[EPB];
    __shared__ int gposa[EPB];
    __shared__ int wpart[8];
    __shared__ int tot_s;

    int tid = threadIdx.x;
    int e0 = blockIdx.x * EPB;
    int lane = tid & 63, wv = tid >> 6;

    if (tid < 512) { cnt[tid] = 0; run[tid] = 0; }

    // ---- fused convert slice: x (f32) -> xb (bf16), ~4 float4/thread ----
    for (int i = blockIdx.x * 1024 + tid; i < N_NODES * D / 4;
         i += SORT_BLOCKS * 1024) {
        float4 v = ((const float4*)x)[i];
        ushort4 o;
        o.x = f2bf(v.x); o.y = f2bf(v.y); o.z = f2bf(v.z); o.w = f2bf(v.w);
        ((ushort4*)xb)[i] = o;
    }

    // ---- register-stage this thread's 4 edges + hist ----
    int limit = min(EPB, N_EDGES - e0);   // 4096 or 2560 (both %4 == 0)
    int g0 = 4 * tid;
    bool have = g0 < limit;
    uint4 src4, dst4;
    __syncthreads();   // cnt/run zero visible
    if (have) {
        src4 = *(const uint4*)(ei + e0 + g0);
        dst4 = *(const uint4*)(ei + N_EDGES + e0 + g0);
        atomicAdd(&cnt[((int)dst4.x) >> 8], 1);
        atomicAdd(&cnt[((int)dst4.y) >> 8], 1);
        atomicAdd(&cnt[((int)dst4.z) >> 8], 1);
        atomicAdd(&cnt[((int)dst4.w) >> 8], 1);
    }
    __syncthreads();

    // ---- 512-wide exclusive scan: 8 waves shfl-scan 64 each + combine ----
    int inc = 0, v = 0;
    if (tid < 512) {
        v = cnt[tid];
        inc = v;
        for (int off = 1; off < 64; off <<= 1) {
            int t = __shfl_up(inc, off);
            if (lane >= off) inc += t;
        }
        if (lane == 63) wpart[wv] = inc;
    }
    __syncthreads();
    if (tid < 64) {
        int p = (lane < 8) ? wpart[lane] : 0;
        int ps = p;
        for (int off = 1; off < 8; off <<= 1) {
            int t = __shfl_up(ps, off);
            if (lane >= off) ps += t;
        }
        if (lane < 8) wpart[lane] = ps - p;   // exclusive wave base
    }
    __syncthreads();
    if (tid < 512) {
        base_s[tid] = wpart[wv] + inc - v;    // exclusive prefix
        if (tid == 511) tot_s = wpart[7] + inc;
    }
    // ---- reserve global queue space (one atomic per nonempty bucket) ----
    if (tid < NBUCKET && cnt[tid] > 0)
        gbase[tid] = atomicAdd(&qtail[tid], cnt[tid]);
    __syncthreads();

    // ---- scatter into bucket-sorted LDS staging (from registers) ----
    if (have) {
        int ss[4] = {(int)src4.x, (int)src4.y, (int)src4.z, (int)src4.w};
        int dd[4] = {(int)dst4.x, (int)dst4.y, (int)dst4.z, (int)dst4.w};
#pragma unroll
        for (int q = 0; q < 4; ++q) {
            int b = dd[q] >> 8;
            int r = atomicAdd(&run[b], 1);
            int slot = base_s[b] + r;
            staged[slot] = ((unsigned)(dd[q] & 255) << 17) | (unsigned)ss[q];
            int gp = gbase[b] + r;
            gposa[slot] = (gp < QCAP_B) ? b * QCAP_B + gp : -1;
        }
    }
    __syncthreads();

    // ---- copy out (bucket-contiguous runs): 4 iters ----
    int total = tot_s;
    for (int i = tid; i < total; i += 1024) {
        int gp = gposa[i];
        if (gp >= 0) queue[gp] = staged[i];
    }
}

// ---------------------------------------------------------------------------
// Per-bucket LDS counting sort -> exact CSR. Zero global atomics.
// 1024 threads, wave-shfl scan (r7 version, verbatim).
// ---------------------------------------------------------------------------
__global__ __launch_bounds__(1024) void bin3_kernel(
    const unsigned* __restrict__ queue, const int* __restrict__ qtail,
    int* __restrict__ cnt_out, int* __restrict__ row_start,
    int* __restrict__ sorted_src)
{
    __shared__ int cnt[256];
    __shared__ int ebase[256];
    __shared__ int run[256];
    __shared__ unsigned staged[QCAP_B];
    __shared__ int wpart[8];

    int tid = threadIdx.x;
    int b = blockIdx.x;
    int lane = tid & 63, wv = tid >> 6;

    if (tid < 256) { cnt[tid] = 0; run[tid] = 0; }
    __syncthreads();

    int n = min(qtail[b], QCAP_B);
    const unsigned* q = queue + (size_t)b * QCAP_B;

    // ---- stage + hist: ~4 iters ----
    for (int i = tid; i < n; i += 1024) {
        unsigned e = q[i];
        staged[i] = e;
        atomicAdd(&cnt[e >> 17], 1);
    }
    __syncthreads();

    // ---- 256-wide exclusive scan: 4 waves shfl-scan + combine ----
    int inc = 0, v = 0;
    if (tid < 256) {
        v = cnt[tid];
        inc = v;
        for (int off = 1; off < 64; off <<= 1) {
            int t = __shfl_up(inc, off);
            if (lane >= off) inc += t;
        }
        if (lane == 63) wpart[wv] = inc;
    }
    __syncthreads();
    if (tid < 64) {
        int p = (lane < 4) ? wpart[lane] : 0;
        int ps = p;
        for (int off = 1; off < 4; off <<= 1) {
            int t = __shfl_up(ps, off);
            if (lane >= off) ps += t;
        }
        if (lane < 4) wpart[lane] = ps - p;
    }
    __syncthreads();

    int gb = b * QCAP_B;
    if (tid < 256) {
        int eb = wpart[wv] + inc - v;         // exclusive prefix
        ebase[tid] = eb;
        int node = b * 256 + tid;
        if (node < N_NODES) {
            cnt_out[node] = v;
            row_start[node] = gb + eb;
        }
    }
    __syncthreads();

    // ---- scatter into per-node CSR segments: ~4 iters ----
    for (int i = tid; i < n; i += 1024) {
        unsigned e = staged[i];
        int r = (int)(e >> 17);
        int k = atomicAdd(&run[r], 1);
        sorted_src[gb + ebase[r] + k] = (int)(e & 0x1FFFFu);
    }
}

// ---------------------------------------------------------------------------
// Gather aggregation (r1 body — measured best): 8 nodes/wave, 8 lanes/node,
// 16B/lane. One global_load_dwordx4 retires 8 edges per wave instruction.
// Edge indices: coalesced per-lane load + ds_bpermute broadcast within the
// 8-lane group. Consecutive nodes -> contiguous self-rows / index segments /
// output store. Tail edges pad to zeroed dummy row N_NODES.
// NEW: non-temporal loads (via ext-vector u32x4) on the gather rows and the
// streamed index reads (zero L1 reuse -> skip L1 fill, free the MSHR path).
// ---------------------------------------------------------------------------
__global__ __launch_bounds__(256) void aggregate_kernel(
    const u16* __restrict__ xb, const int* __restrict__ cnt_arr,
    const int* __restrict__ row_start, const int* __restrict__ sorted_src,
    u16* __restrict__ xa)
{
    int tid  = threadIdx.x;
    int lane = tid & 63;
    int w    = tid >> 6;
    int g    = lane >> 3;        // group (node within wave)
    int k    = lane & 7;         // 16B chunk within row / edge slot in batch
    int node = blockIdx.x * 32 + w * 8 + g;   // 3125 blocks * 32 = 100000 exact

    int cnt  = cnt_arr[node];
    int base = row_start[node];

    // self-row init: acc = x[node]  (accl[i]=col k*8+2i, acch[i]=col k*8+2i+1)
    const u32x4 sv = *(const u32x4*)(xb + ((size_t)node * D + k * 8));
    float accl[4], acch[4];
#pragma unroll
    for (int i = 0; i < 4; ++i) {
        unsigned d = sv[i];
        unsigned lo = d << 16, hi = d & 0xFFFF0000u;
        __builtin_memcpy(&accl[i], &lo, 4);
        __builtin_memcpy(&acch[i], &hi, 4);
    }

    // wave max degree across the 8 groups -> common trip count
    int mc = cnt;
    mc = max(mc, __shfl_xor(mc, 8));
    mc = max(mc, __shfl_xor(mc, 16));
    mc = max(mc, __shfl_xor(mc, 32));

    int lb4 = (lane & 56) << 2;  // byte addr of group's lane 0 for bpermute

    for (int c = 0; c < mc; c += 8) {
        // lane k holds edge c+k's source index for its group;
        // past-degree slots point at the zeroed dummy row N_NODES.
        int s = (c + k < cnt) ? __builtin_nontemporal_load(sorted_src + base + c + k)
                              : N_NODES;

        u32x4 v[8];
#pragma unroll
        for (int j = 0; j < 8; ++j) {
            int idx = __builtin_amdgcn_ds_bpermute(lb4 + 4 * j, s);
            v[j] = __builtin_nontemporal_load(
                (const u32x4*)(xb + (((size_t)(unsigned)idx) * D + (k << 3))));
        }
#pragma unroll
        for (int j = 0; j < 8; ++j) {
#pragma unroll
            for (int i = 0; i < 4; ++i) {
                unsigned d = v[j][i];
                unsigned lo = d << 16, hi = d & 0xFFFF0000u;
                float fl, fh;
                __builtin_memcpy(&fl, &lo, 4);
                __builtin_memcpy(&fh, &hi, 4);
                accl[i] += fl;
                acch[i] += fh;
            }
        }
    }

    // pack to bf16 pairs and store this lane's 16B of the row
    u32x4 outv;
#pragma unroll
    for (int i = 0; i < 4; ++i) {
        unsigned b0 = f2bf(accl[i]);
        unsigned b1 = f2bf(acch[i]);
        outv[i] = b0 | (b1 << 16);
    }
    *(u32x4*)(xa + ((size_t)node * D + k * 8)) = outv;
}

// ---------------------------------------------------------------------------
// MFMA MLP: out = [relu?]( relu(xa@W1+b1) @ W2 + b2 ), bf16 in, fp32 acc.
// Block = 256 = 4 waves; wave = 16 nodes x all 64 cols.
// A-frags (A[m=lane&15][k=quad*8+j], m120-verified) load DIRECTLY from
// global xa: one dwordx4 per K-half (wave covers a contiguous 2KB window).
// B-frags: prepacked Wf, one dwordx4 per frag. C/D layout (m89-verified):
// col=lane&15, row=quad*4+reg. Hidden u round-trips through WAVE-PRIVATE
// LDS rows (stride 136B -> layer-2 A-frag ds_read_b64 pairs, <=4-way
// aliased); no __syncthreads needed.
// ---------------------------------------------------------------------------
#define US 68   // u16 stride per node row (136 B)

template <int WRITE_BF16>
__global__ __launch_bounds__(256) void gin_mlp_kernel(
    const u16* __restrict__ xa, const u16* __restrict__ Wf,
    const float* __restrict__ b1, const float* __restrict__ b2,
    float* __restrict__ outf, u16* __restrict__ outb)
{
    __shared__ u16 us[64 * US];   // 8704 B

    int tid  = threadIdx.x;
    int lane = tid & 63;
    int w    = tid >> 6;
    int quad = lane >> 4;
    int l16  = lane & 15;
    int n0   = blockIdx.x * 64 + w * 16;

    // ---- layer 1: u = relu(xa @ W1 + b1) ----
    int arow = min(n0 + l16, N_NODES - 1);
    const u16* ab = xa + (size_t)arow * D + quad * 8;
    bf16x8 a0 = *(const bf16x8*)ab;          // k = quad*8+j
    bf16x8 a1 = *(const bf16x8*)(ab + 32);   // k = 32+quad*8+j

    f32x4 acc[4];
#pragma unroll
    for (int ct = 0; ct < 4; ++ct) {
        float bv = b1[ct * 16 + l16];
        acc[ct] = (f32x4){bv, bv, bv, bv};
        bf16x8 bf0 = *(const bf16x8*)(Wf + (size_t)((0 * 4 + ct) * 2 + 0) * 512 + lane * 8);
        bf16x8 bf1 = *(const bf16x8*)(Wf + (size_t)((0 * 4 + ct) * 2 + 1) * 512 + lane * 8);
        acc[ct] = __builtin_amdgcn_mfma_f32_16x16x32_bf16(a0, bf0, acc[ct], 0, 0, 0);
        acc[ct] = __builtin_amdgcn_mfma_f32_16x16x32_bf16(a1, bf1, acc[ct], 0, 0, 0);
    }

    // relu -> bf16 -> wave-private LDS rows (C-layout: row=quad*4+r, col)
#pragma unroll
    for (int ct = 0; ct < 4; ++ct)
#pragma unroll
        for (int r = 0; r < 4; ++r)
            us[(w * 16 + quad * 4 + r) * US + ct * 16 + l16] =
                f2bf(fmaxf(acc[ct][r], 0.f));

    // ---- layer 2: v = u @ W2 + b2 ----
    const u16* ub = &us[(w * 16 + l16) * US + quad * 8];
    s16x4 lo0 = *(const s16x4*)ub;
    s16x4 hi0 = *(const s16x4*)(ub + 4);
    s16x4 lo1 = *(const s16x4*)(ub + 32);
    s16x4 hi1 = *(const s16x4*)(ub + 36);
    bf16x8 u0 = __builtin_shufflevector(lo0, hi0, 0, 1, 2, 3, 4, 5, 6, 7);
    bf16x8 u1 = __builtin_shufflevector(lo1, hi1, 0, 1, 2, 3, 4, 5, 6, 7);

#pragma unroll
    for (int ct = 0; ct < 4; ++ct) {
        float bv = b2[ct * 16 + l16];
        acc[ct] = (f32x4){bv, bv, bv, bv};
        bf16x8 bf0 = *(const bf16x8*)(Wf + (size_t)((1 * 4 + ct) * 2 + 0) * 512 + lane * 8);
        bf16x8 bf1 = *(const bf16x8*)(Wf + (size_t)((1 * 4 + ct) * 2 + 1) * 512 + lane * 8);
        acc[ct] = __builtin_amdgcn_mfma_f32_16x16x32_bf16(u0, bf0, acc[ct], 0, 0, 0);
        acc[ct] = __builtin_amdgcn_mfma_f32_16x16x32_bf16(u1, bf1, acc[ct], 0, 0, 0);
    }

    // epilogue (C-layout scatter; 16-lane groups write contiguous runs)
#pragma unroll
    for (int r = 0; r < 4; ++r) {
        int node = n0 + quad * 4 + r;
        if (node >= N_NODES) continue;
#pragma unroll
        for (int ct = 0; ct < 4; ++ct) {
            if (WRITE_BF16)
                outb[(size_t)node * D + ct * 16 + l16] = f2bf(fmaxf(acc[ct][r], 0.f));
            else
                outf[(size_t)node * D + ct * 16 + l16] = acc[ct][r];
        }
    }
}

extern "C" void kernel_launch(void* const* d_in, const int* in_sizes, int n_in,
                              void* d_out, int out_size, void* d_ws, size_t ws_size,
                              hipStream_t stream)
{
    const float* x  = (const float*)d_in[0];
    const int*   ei = (const int*)d_in[1];
    const float* W1 = (const float*)d_in[2];
    const float* b1 = (const float*)d_in[3];
    const float* W2 = (const float*)d_in[4];
    const float* b2 = (const float*)d_in[5];
    float* out = (float*)d_out;

    // workspace (~41.5 MB):
    //   qtail(512) | cnt(100096) | row_start(100096)
    //   queue (391*4800 u32) | sorted_src (391*4800 int)
    //   Wf (8192 u16) | xa (N rows bf16) | xb ((N+1) rows bf16, also holds hb)
    int* qtail      = (int*)d_ws;
    int* cnt_arr    = qtail + 512;
    int* row_start  = cnt_arr + 100096;
    unsigned* queue = (unsigned*)(row_start + 100096);
    int* sorted_src = (int*)(queue + (size_t)NBUCKET * QCAP_B);
    u16* Wf         = (u16*)(sorted_src + (size_t)NBUCKET * QCAP_B);
    u16* xa_b       = Wf + 8192;
    u16* xb_b       = xa_b + (size_t)N_NODES * D;

    const int agg_blocks = (N_NODES + 31) / 32;     // 3125 (8 nodes/wave)
    const int mlp_blocks = (N_NODES + 63) / 64;     // 1563

    // ---- prep: misc (qtail, dummy row, weights) then sort(+convert) ----
    misc_kernel<<<1, 256, 0, stream>>>(W1, W2, Wf, qtail, xb_b);
    sort_kernel<<<SORT_BLOCKS, 1024, 0, stream>>>(ei, qtail, queue, x, xb_b);
    bin3_kernel<<<NBUCKET, 1024, 0, stream>>>(queue, qtail, cnt_arr, row_start, sorted_src);

    // ---- layer 1: hb(xb_b) = relu(MLP(xb + gather(xb))) ----
    aggregate_kernel<<<agg_blocks, 256, 0, stream>>>(xb_b, cnt_arr, row_start, sorted_src, xa_b);
    gin_mlp_kernel<1><<<mlp_blocks, 256, 0, stream>>>(xa_b, Wf, b1, b2, nullptr, xb_b);

    // ---- layer 2: out = MLP(hb + gather(hb)) ----
    aggregate_kernel<<<agg_blocks, 256, 0, stream>>>(xb_b, cnt_arr, row_start, sorted_src, xa_b);
    gin_mlp_kernel<0><<<mlp_blocks, 256, 0, stream>>>(xa_b, Wf, b1, b2, out, nullptr);
}

// Round 11
// 192.908 us; speedup vs baseline: 1.1069x; 1.1069x over previous
//
#include <hip/hip_runtime.h>

#define N_NODES 100000
#define N_EDGES 1600000
#define D 64
#define NBUCKET 782              // ceil(N_NODES/128), bucket = 128 dst nodes
#define QCAP_B 2432              // per-bucket queue cap (mean ~2046, +8.5 sd)
#define EPB 4096                 // edges per sort block
#define SORT_BLOCKS 391          // ceil(N_EDGES/EPB)

typedef unsigned short u16;
typedef short bf16x8 __attribute__((ext_vector_type(8)));
typedef short s16x4  __attribute__((ext_vector_type(4)));
typedef float f32x4  __attribute__((ext_vector_type(4)));

__device__ __forceinline__ float bf2f(u16 u) {
    unsigned v = (unsigned)u << 16;
    float f;
    __builtin_memcpy(&f, &v, 4);
    return f;
}
__device__ __forceinline__ u16 f2bf(float f) {
    unsigned u;
    __builtin_memcpy(&u, &f, 4);
    u = (u + 0x7FFFu + ((u >> 16) & 1u)) >> 16;
    return (u16)u;
}

// ---------------------------------------------------------------------------
// Tiny prep (1 block): qtail zero (must precede sort's atomics), dummy-row
// zero, W1/W2 -> bf16 MFMA B-fragment pack.
// frag f = (layer*4 + ct)*2 + kf holds B[k=kf*32+quad*8+j][n=ct*16+(lane&15)]
// at u16 offset f*512 + lane*8 + j.
// ---------------------------------------------------------------------------
__global__ __launch_bounds__(256) void misc_kernel(
    const float* __restrict__ W1, const float* __restrict__ W2,
    u16* __restrict__ Wf, int* __restrict__ qtail, u16* __restrict__ xb)
{
    int tid = threadIdx.x;
#pragma unroll
    for (int q = 0; q < 4; ++q)
        qtail[tid + q * 256] = 0;
    if (tid < 32)
        ((unsigned*)(xb + (size_t)N_NODES * D))[tid] = 0;
#pragma unroll
    for (int t = tid; t < 16 * 64; t += 256) {
        int f = t >> 6, lane = t & 63;
        int layer = f >> 3, ct = (f >> 1) & 3, kf = f & 1;
        const float* W = layer ? W2 : W1;
        int col = ct * 16 + (lane & 15);
        int krow = kf * 32 + (lane >> 4) * 8;
        u16* o = Wf + f * 512 + lane * 8;
#pragma unroll
        for (int j = 0; j < 8; ++j)
            o[j] = f2bf(W[(krow + j) * D + col]);
    }
}

// ---------------------------------------------------------------------------
// Block-level counting sort of 4096 edges into 782 bucket queues.
// 1024 threads, 16-wave shfl scan over 1024 bucket counters, register-staged
// ei (each thread owns 4 contiguous edges loaded once as two uint4), PLUS the
// bulk x->bf16 convert grid-strided across the kernel (HBM work hidden under
// sort latency). Entry packs (dst&127)<<17 | src.
// ---------------------------------------------------------------------------
__global__ __launch_bounds__(1024) void sort_kernel(
    const int* __restrict__ ei, int* __restrict__ qtail,
    unsigned* __restrict__ queue, const float* __restrict__ x,
    u16* __restrict__ xb)
{
    __shared__ int cnt[1024];
    __shared__ int base_s[1024];
    __shared__ int gbase[1024];
    __shared__ int run[1024];
    __shared__ unsigned staged[EPB];
    __shared__ int gposa[EPB];
    __shared__ int wpart[16];
    __shared__ int tot_s;

    int tid = threadIdx.x;
    int e0 = blockIdx.x * EPB;
    int lane = tid & 63, wv = tid >> 6;

    cnt[tid] = 0; run[tid] = 0;

    // ---- fused convert slice: x (f32) -> xb (bf16), ~4 float4/thread ----
    for (int i = blockIdx.x * 1024 + tid; i < N_NODES * D / 4;
         i += SORT_BLOCKS * 1024) {
        float4 v = ((const float4*)x)[i];
        ushort4 o;
        o.x = f2bf(v.x); o.y = f2bf(v.y); o.z = f2bf(v.z); o.w = f2bf(v.w);
        ((ushort4*)xb)[i] = o;
    }

    // ---- register-stage this thread's 4 edges + hist ----
    int limit = min(EPB, N_EDGES - e0);   // 4096 or 2560 (both %4 == 0)
    int g0 = 4 * tid;
    bool have = g0 < limit;
    uint4 src4, dst4;
    __syncthreads();   // cnt/run zero visible
    if (have) {
        src4 = *(const uint4*)(ei + e0 + g0);
        dst4 = *(const uint4*)(ei + N_EDGES + e0 + g0);
        atomicAdd(&cnt[((int)dst4.x) >> 7], 1);
        atomicAdd(&cnt[((int)dst4.y) >> 7], 1);
        atomicAdd(&cnt[((int)dst4.z) >> 7], 1);
        atomicAdd(&cnt[((int)dst4.w) >> 7], 1);
    }
    __syncthreads();

    // ---- 1024-wide exclusive scan: 16 waves shfl-scan 64 each + combine ----
    int v = cnt[tid];
    int inc = v;
    for (int off = 1; off < 64; off <<= 1) {
        int t = __shfl_up(inc, off);
        if (lane >= off) inc += t;
    }
    if (lane == 63) wpart[wv] = inc;
    __syncthreads();
    if (tid < 64) {
        int p = (lane < 16) ? wpart[lane] : 0;
        int ps = p;
        for (int off = 1; off < 16; off <<= 1) {
            int t = __shfl_up(ps, off);
            if (lane >= off) ps += t;
        }
        if (lane < 16) wpart[lane] = ps - p;   // exclusive wave base
    }
    __syncthreads();
    base_s[tid] = wpart[wv] + inc - v;         // exclusive prefix
    if (tid == 1023) tot_s = wpart[15] + inc;
    // ---- reserve global queue space (one atomic per nonempty bucket) ----
    if (tid < NBUCKET && cnt[tid] > 0)
        gbase[tid] = atomicAdd(&qtail[tid], cnt[tid]);
    __syncthreads();

    // ---- scatter into bucket-sorted LDS staging (from registers) ----
    if (have) {
        int ss[4] = {(int)src4.x, (int)src4.y, (int)src4.z, (int)src4.w};
        int dd[4] = {(int)dst4.x, (int)dst4.y, (int)dst4.z, (int)dst4.w};
#pragma unroll
        for (int q = 0; q < 4; ++q) {
            int b = dd[q] >> 7;
            int r = atomicAdd(&run[b], 1);
            int slot = base_s[b] + r;
            staged[slot] = ((unsigned)(dd[q] & 127) << 17) | (unsigned)ss[q];
            int gp = gbase[b] + r;
            gposa[slot] = (gp < QCAP_B) ? b * QCAP_B + gp : -1;
        }
    }
    __syncthreads();

    // ---- copy out (bucket-contiguous runs): 4 iters ----
    int total = tot_s;
    for (int i = tid; i < total; i += 1024) {
        int gp = gposa[i];
        if (gp >= 0) queue[gp] = staged[i];
    }
}

// ---------------------------------------------------------------------------
// Per-bucket LDS counting sort -> exact CSR. Zero global atomics.
// v3: 128-node buckets -> 782 blocks x 512 threads (8 waves) -> ~4 blocks/CU
// resident (vs 1.5 at 256-node buckets), ~3x the per-edge-pass parallelism.
// ---------------------------------------------------------------------------
__global__ __launch_bounds__(512) void bin3_kernel(
    const unsigned* __restrict__ queue, const int* __restrict__ qtail,
    int* __restrict__ cnt_out, int* __restrict__ row_start,
    int* __restrict__ sorted_src)
{
    __shared__ int cnt[128];
    __shared__ int ebase[128];
    __shared__ int run[128];
    __shared__ unsigned staged[QCAP_B];
    __shared__ int wpart[2];

    int tid = threadIdx.x;
    int b = blockIdx.x;
    int lane = tid & 63, wv = tid >> 6;

    if (tid < 128) { cnt[tid] = 0; run[tid] = 0; }
    __syncthreads();

    int n = min(qtail[b], QCAP_B);
    const unsigned* q = queue + (size_t)b * QCAP_B;

    // ---- stage + hist: ~4 iters ----
    for (int i = tid; i < n; i += 512) {
        unsigned e = q[i];
        staged[i] = e;
        atomicAdd(&cnt[e >> 17], 1);
    }
    __syncthreads();

    // ---- 128-wide exclusive scan: 2 waves shfl-scan + tiny combine ----
    int inc = 0, v = 0;
    if (tid < 128) {
        v = cnt[tid];
        inc = v;
        for (int off = 1; off < 64; off <<= 1) {
            int t = __shfl_up(inc, off);
            if (lane >= off) inc += t;
        }
        if (lane == 63) wpart[wv] = inc;
    }
    __syncthreads();
    if (tid == 0) { int a = wpart[0]; wpart[0] = 0; wpart[1] = a; }
    __syncthreads();

    int gb = b * QCAP_B;
    if (tid < 128) {
        int eb = wpart[wv] + inc - v;         // exclusive prefix
        ebase[tid] = eb;
        int node = b * 128 + tid;
        if (node < N_NODES) {
            cnt_out[node] = v;
            row_start[node] = gb + eb;
        }
    }
    __syncthreads();

    // ---- scatter into per-node CSR segments: ~4 iters ----
    for (int i = tid; i < n; i += 512) {
        unsigned e = staged[i];
        int r = (int)(e >> 17);
        int k = atomicAdd(&run[r], 1);
        sorted_src[gb + ebase[r] + k] = (int)(e & 0x1FFFFu);
    }
}

// ---------------------------------------------------------------------------
// Gather aggregation (r1 body, verbatim — measured best across 6 variants):
// 8 nodes/wave, 8 lanes/node, 16B/lane. One global_load_dwordx4 retires 8
// edges per wave instruction. Edge indices: coalesced per-lane load +
// ds_bpermute broadcast within the 8-lane group. Consecutive nodes ->
// contiguous self-rows / index segments / output store. Tail edges pad to
// zeroed dummy row N_NODES. NO nt hints (r10: nt cost +9us — xb has ~58%
// cache-hit reuse that nt bypassed).
// ---------------------------------------------------------------------------
__global__ __launch_bounds__(256) void aggregate_kernel(
    const u16* __restrict__ xb, const int* __restrict__ cnt_arr,
    const int* __restrict__ row_start, const int* __restrict__ sorted_src,
    u16* __restrict__ xa)
{
    int tid  = threadIdx.x;
    int lane = tid & 63;
    int w    = tid >> 6;
    int g    = lane >> 3;        // group (node within wave)
    int k    = lane & 7;         // 16B chunk within row / edge slot in batch
    int node = blockIdx.x * 32 + w * 8 + g;   // 3125 blocks * 32 = 100000 exact

    int cnt  = cnt_arr[node];
    int base = row_start[node];

    // self-row init: acc = x[node]  (accl[i]=col k*8+2i, acch[i]=col k*8+2i+1)
    const uint4 sv = *(const uint4*)(xb + ((size_t)node * D + k * 8));
    float accl[4], acch[4];
#pragma unroll
    for (int i = 0; i < 4; ++i) {
        unsigned d = ((const unsigned*)&sv)[i];
        unsigned lo = d << 16, hi = d & 0xFFFF0000u;
        __builtin_memcpy(&accl[i], &lo, 4);
        __builtin_memcpy(&acch[i], &hi, 4);
    }

    // wave max degree across the 8 groups -> common trip count
    int mc = cnt;
    mc = max(mc, __shfl_xor(mc, 8));
    mc = max(mc, __shfl_xor(mc, 16));
    mc = max(mc, __shfl_xor(mc, 32));

    int lb4 = (lane & 56) << 2;  // byte addr of group's lane 0 for bpermute

    for (int c = 0; c < mc; c += 8) {
        // lane k holds edge c+k's source index for its group;
        // past-degree slots point at the zeroed dummy row N_NODES.
        int s = (c + k < cnt) ? sorted_src[base + c + k] : N_NODES;

        uint4 v[8];
#pragma unroll
        for (int j = 0; j < 8; ++j) {
            int idx = __builtin_amdgcn_ds_bpermute(lb4 + 4 * j, s);
            v[j] = *(const uint4*)(xb + (((size_t)(unsigned)idx) * D + (k << 3)));
        }
#pragma unroll
        for (int j = 0; j < 8; ++j) {
#pragma unroll
            for (int i = 0; i < 4; ++i) {
                unsigned d = ((const unsigned*)&v[j])[i];
                unsigned lo = d << 16, hi = d & 0xFFFF0000u;
                float fl, fh;
                __builtin_memcpy(&fl, &lo, 4);
                __builtin_memcpy(&fh, &hi, 4);
                accl[i] += fl;
                acch[i] += fh;
            }
        }
    }

    // pack to bf16 pairs and store this lane's 16B of the row
    unsigned out[4];
#pragma unroll
    for (int i = 0; i < 4; ++i) {
        unsigned b0 = f2bf(accl[i]);
        unsigned b1 = f2bf(acch[i]);
        out[i] = b0 | (b1 << 16);
    }
    *(uint4*)(xa + ((size_t)node * D + k * 8)) = *(const uint4*)out;
}

// ---------------------------------------------------------------------------
// MFMA MLP: out = [relu?]( relu(xa@W1+b1) @ W2 + b2 ), bf16 in, fp32 acc.
// Block = 256 = 4 waves; wave = 16 nodes x all 64 cols.
// A-frags (A[m=lane&15][k=quad*8+j], m120-verified) load DIRECTLY from
// global xa: one dwordx4 per K-half (wave covers a contiguous 2KB window).
// B-frags: prepacked Wf, one dwordx4 per frag. C/D layout (m89-verified):
// col=lane&15, row=quad*4+reg. Hidden u round-trips through WAVE-PRIVATE
// LDS rows (stride 136B -> layer-2 A-frag ds_read_b64 pairs, <=4-way
// aliased); no __syncthreads needed.
// ---------------------------------------------------------------------------
#define US 68   // u16 stride per node row (136 B)

template <int WRITE_BF16>
__global__ __launch_bounds__(256) void gin_mlp_kernel(
    const u16* __restrict__ xa, const u16* __restrict__ Wf,
    const float* __restrict__ b1, const float* __restrict__ b2,
    float* __restrict__ outf, u16* __restrict__ outb)
{
    __shared__ u16 us[64 * US];   // 8704 B

    int tid  = threadIdx.x;
    int lane = tid & 63;
    int w    = tid >> 6;
    int quad = lane >> 4;
    int l16  = lane & 15;
    int n0   = blockIdx.x * 64 + w * 16;

    // ---- layer 1: u = relu(xa @ W1 + b1) ----
    int arow = min(n0 + l16, N_NODES - 1);
    const u16* ab = xa + (size_t)arow * D + quad * 8;
    bf16x8 a0 = *(const bf16x8*)ab;          // k = quad*8+j
    bf16x8 a1 = *(const bf16x8*)(ab + 32);   // k = 32+quad*8+j

    f32x4 acc[4];
#pragma unroll
    for (int ct = 0; ct < 4; ++ct) {
        float bv = b1[ct * 16 + l16];
        acc[ct] = (f32x4){bv, bv, bv, bv};
        bf16x8 bf0 = *(const bf16x8*)(Wf + (size_t)((0 * 4 + ct) * 2 + 0) * 512 + lane * 8);
        bf16x8 bf1 = *(const bf16x8*)(Wf + (size_t)((0 * 4 + ct) * 2 + 1) * 512 + lane * 8);
        acc[ct] = __builtin_amdgcn_mfma_f32_16x16x32_bf16(a0, bf0, acc[ct], 0, 0, 0);
        acc[ct] = __builtin_amdgcn_mfma_f32_16x16x32_bf16(a1, bf1, acc[ct], 0, 0, 0);
    }

    // relu -> bf16 -> wave-private LDS rows (C-layout: row=quad*4+r, col)
#pragma unroll
    for (int ct = 0; ct < 4; ++ct)
#pragma unroll
        for (int r = 0; r < 4; ++r)
            us[(w * 16 + quad * 4 + r) * US + ct * 16 + l16] =
                f2bf(fmaxf(acc[ct][r], 0.f));

    // ---- layer 2: v = u @ W2 + b2 ----
    const u16* ub = &us[(w * 16 + l16) * US + quad * 8];
    s16x4 lo0 = *(const s16x4*)ub;
    s16x4 hi0 = *(const s16x4*)(ub + 4);
    s16x4 lo1 = *(const s16x4*)(ub + 32);
    s16x4 hi1 = *(const s16x4*)(ub + 36);
    bf16x8 u0 = __builtin_shufflevector(lo0, hi0, 0, 1, 2, 3, 4, 5, 6, 7);
    bf16x8 u1 = __builtin_shufflevector(lo1, hi1, 0, 1, 2, 3, 4, 5, 6, 7);

#pragma unroll
    for (int ct = 0; ct < 4; ++ct) {
        float bv = b2[ct * 16 + l16];
        acc[ct] = (f32x4){bv, bv, bv, bv};
        bf16x8 bf0 = *(const bf16x8*)(Wf + (size_t)((1 * 4 + ct) * 2 + 0) * 512 + lane * 8);
        bf16x8 bf1 = *(const bf16x8*)(Wf + (size_t)((1 * 4 + ct) * 2 + 1) * 512 + lane * 8);
        acc[ct] = __builtin_amdgcn_mfma_f32_16x16x32_bf16(u0, bf0, acc[ct], 0, 0, 0);
        acc[ct] = __builtin_amdgcn_mfma_f32_16x16x32_bf16(u1, bf1, acc[ct], 0, 0, 0);
    }

    // epilogue (C-layout scatter; 16-lane groups write contiguous runs)
#pragma unroll
    for (int r = 0; r < 4; ++r) {
        int node = n0 + quad * 4 + r;
        if (node >= N_NODES) continue;
#pragma unroll
        for (int ct = 0; ct < 4; ++ct) {
            if (WRITE_BF16)
                outb[(size_t)node * D + ct * 16 + l16] = f2bf(fmaxf(acc[ct][r], 0.f));
            else
                outf[(size_t)node * D + ct * 16 + l16] = acc[ct][r];
        }
    }
}

extern "C" void kernel_launch(void* const* d_in, const int* in_sizes, int n_in,
                              void* d_out, int out_size, void* d_ws, size_t ws_size,
                              hipStream_t stream)
{
    const float* x  = (const float*)d_in[0];
    const int*   ei = (const int*)d_in[1];
    const float* W1 = (const float*)d_in[2];
    const float* b1 = (const float*)d_in[3];
    const float* W2 = (const float*)d_in[4];
    const float* b2 = (const float*)d_in[5];
    float* out = (float*)d_out;

    // workspace (~41.6 MB):
    //   qtail(1024) | cnt(100096) | row_start(100096)
    //   queue (782*2432 u32) | sorted_src (782*2432 int)
    //   Wf (8192 u16) | xa (N rows bf16) | xb ((N+1) rows bf16, also holds hb)
    int* qtail      = (int*)d_ws;
    int* cnt_arr    = qtail + 1024;
    int* row_start  = cnt_arr + 100096;
    unsigned* queue = (unsigned*)(row_start + 100096);
    int* sorted_src = (int*)(queue + (size_t)NBUCKET * QCAP_B);
    u16* Wf         = (u16*)(sorted_src + (size_t)NBUCKET * QCAP_B);
    u16* xa_b       = Wf + 8192;
    u16* xb_b       = xa_b + (size_t)N_NODES * D;

    const int agg_blocks = (N_NODES + 31) / 32;     // 3125 (8 nodes/wave)
    const int mlp_blocks = (N_NODES + 63) / 64;     // 1563

    // ---- prep: misc (qtail, dummy row, weights) then sort(+convert) ----
    misc_kernel<<<1, 256, 0, stream>>>(W1, W2, Wf, qtail, xb_b);
    sort_kernel<<<SORT_BLOCKS, 1024, 0, stream>>>(ei, qtail, queue, x, xb_b);
    bin3_kernel<<<NBUCKET, 512, 0, stream>>>(queue, qtail, cnt_arr, row_start, sorted_src);

    // ---- layer 1: hb(xb_b) = relu(MLP(xb + gather(xb))) ----
    aggregate_kernel<<<agg_blocks, 256, 0, stream>>>(xb_b, cnt_arr, row_start, sorted_src, xa_b);
    gin_mlp_kernel<1><<<mlp_blocks, 256, 0, stream>>>(xa_b, Wf, b1, b2, nullptr, xb_b);

    // ---- layer 2: out = MLP(hb + gather(hb)) ----
    aggregate_kernel<<<agg_blocks, 256, 0, stream>>>(xb_b, cnt_arr, row_start, sorted_src, xa_b);
    gin_mlp_kernel<0><<<mlp_blocks, 256, 0, stream>>>(xa_b, Wf, b1, b2, out, nullptr);
}

// Round 12
// 183.819 us; speedup vs baseline: 1.1617x; 1.0494x over previous
//
#include <hip/hip_runtime.h>

#define N_NODES 100000
#define N_EDGES 1600000
#define D 64
#define NBUCKET 782              // ceil(N_NODES/128), bucket = 128 dst nodes
#define QCAP_B 2432              // per-bucket queue cap (mean ~2046, +8.5 sd)
#define EPB 4096                 // edges per sort block
#define SORT_BLOCKS 391          // ceil(N_EDGES/EPB)

typedef unsigned short u16;
typedef short bf16x8 __attribute__((ext_vector_type(8)));
typedef float f32x4  __attribute__((ext_vector_type(4)));

__device__ __forceinline__ u16 f2bf(float f) {
    unsigned u;
    __builtin_memcpy(&u, &f, 4);
    u = (u + 0x7FFFu + ((u >> 16) & 1u)) >> 16;
    return (u16)u;
}

// ---------------------------------------------------------------------------
// Tiny prep (1 block): qtail zero (must precede sort's atomics), dummy-row
// zero in BOTH feature buffers (xb for layer1 pads, hb for layer2 pads),
// W1/W2 -> bf16 MFMA B-fragment pack.
// frag f = (layer*4 + ct)*2 + kf holds B[k=kf*32+quad*8+j][n=ct*16+(lane&15)]
// at u16 offset f*512 + lane*8 + j.
// ---------------------------------------------------------------------------
__global__ __launch_bounds__(256) void misc_kernel(
    const float* __restrict__ W1, const float* __restrict__ W2,
    u16* __restrict__ Wf, int* __restrict__ qtail,
    u16* __restrict__ xb, u16* __restrict__ hb)
{
    int tid = threadIdx.x;
#pragma unroll
    for (int q = 0; q < 4; ++q)
        qtail[tid + q * 256] = 0;
    if (tid < 32) {
        ((unsigned*)(xb + (size_t)N_NODES * D))[tid] = 0;
        ((unsigned*)(hb + (size_t)N_NODES * D))[tid] = 0;
    }
#pragma unroll
    for (int t = tid; t < 16 * 64; t += 256) {
        int f = t >> 6, lane = t & 63;
        int layer = f >> 3, ct = (f >> 1) & 3, kf = f & 1;
        const float* W = layer ? W2 : W1;
        int col = ct * 16 + (lane & 15);
        int krow = kf * 32 + (lane >> 4) * 8;
        u16* o = Wf + f * 512 + lane * 8;
#pragma unroll
        for (int j = 0; j < 8; ++j)
            o[j] = f2bf(W[(krow + j) * D + col]);
    }
}

// ---------------------------------------------------------------------------
// Block-level counting sort of 4096 edges into 782 bucket queues (r11,
// verbatim). 1024 threads, 16-wave shfl scan, register-staged ei, fused
// x->bf16 convert. Entry packs (dst&127)<<17 | src.
// ---------------------------------------------------------------------------
__global__ __launch_bounds__(1024) void sort_kernel(
    const int* __restrict__ ei, int* __restrict__ qtail,
    unsigned* __restrict__ queue, const float* __restrict__ x,
    u16* __restrict__ xb)
{
    __shared__ int cnt[1024];
    __shared__ int base_s[1024];
    __shared__ int gbase[1024];
    __shared__ int run[1024];
    __shared__ unsigned staged[EPB];
    __shared__ int gposa[EPB];
    __shared__ int wpart[16];
    __shared__ int tot_s;

    int tid = threadIdx.x;
    int e0 = blockIdx.x * EPB;
    int lane = tid & 63, wv = tid >> 6;

    cnt[tid] = 0; run[tid] = 0;

    // ---- fused convert slice: x (f32) -> xb (bf16), ~4 float4/thread ----
    for (int i = blockIdx.x * 1024 + tid; i < N_NODES * D / 4;
         i += SORT_BLOCKS * 1024) {
        float4 v = ((const float4*)x)[i];
        ushort4 o;
        o.x = f2bf(v.x); o.y = f2bf(v.y); o.z = f2bf(v.z); o.w = f2bf(v.w);
        ((ushort4*)xb)[i] = o;
    }

    // ---- register-stage this thread's 4 edges + hist ----
    int limit = min(EPB, N_EDGES - e0);   // 4096 or 2560 (both %4 == 0)
    int g0 = 4 * tid;
    bool have = g0 < limit;
    uint4 src4, dst4;
    __syncthreads();   // cnt/run zero visible
    if (have) {
        src4 = *(const uint4*)(ei + e0 + g0);
        dst4 = *(const uint4*)(ei + N_EDGES + e0 + g0);
        atomicAdd(&cnt[((int)dst4.x) >> 7], 1);
        atomicAdd(&cnt[((int)dst4.y) >> 7], 1);
        atomicAdd(&cnt[((int)dst4.z) >> 7], 1);
        atomicAdd(&cnt[((int)dst4.w) >> 7], 1);
    }
    __syncthreads();

    // ---- 1024-wide exclusive scan: 16 waves shfl-scan 64 each + combine ----
    int v = cnt[tid];
    int inc = v;
    for (int off = 1; off < 64; off <<= 1) {
        int t = __shfl_up(inc, off);
        if (lane >= off) inc += t;
    }
    if (lane == 63) wpart[wv] = inc;
    __syncthreads();
    if (tid < 64) {
        int p = (lane < 16) ? wpart[lane] : 0;
        int ps = p;
        for (int off = 1; off < 16; off <<= 1) {
            int t = __shfl_up(ps, off);
            if (lane >= off) ps += t;
        }
        if (lane < 16) wpart[lane] = ps - p;   // exclusive wave base
    }
    __syncthreads();
    base_s[tid] = wpart[wv] + inc - v;         // exclusive prefix
    if (tid == 1023) tot_s = wpart[15] + inc;
    // ---- reserve global queue space (one atomic per nonempty bucket) ----
    if (tid < NBUCKET && cnt[tid] > 0)
        gbase[tid] = atomicAdd(&qtail[tid], cnt[tid]);
    __syncthreads();

    // ---- scatter into bucket-sorted LDS staging (from registers) ----
    if (have) {
        int ss[4] = {(int)src4.x, (int)src4.y, (int)src4.z, (int)src4.w};
        int dd[4] = {(int)dst4.x, (int)dst4.y, (int)dst4.z, (int)dst4.w};
#pragma unroll
        for (int q = 0; q < 4; ++q) {
            int b = dd[q] >> 7;
            int r = atomicAdd(&run[b], 1);
            int slot = base_s[b] + r;
            staged[slot] = ((unsigned)(dd[q] & 127) << 17) | (unsigned)ss[q];
            int gp = gbase[b] + r;
            gposa[slot] = (gp < QCAP_B) ? b * QCAP_B + gp : -1;
        }
    }
    __syncthreads();

    // ---- copy out (bucket-contiguous runs): 4 iters ----
    int total = tot_s;
    for (int i = tid; i < total; i += 1024) {
        int gp = gposa[i];
        if (gp >= 0) queue[gp] = staged[i];
    }
}

// ---------------------------------------------------------------------------
// Per-bucket LDS counting sort -> exact CSR (r11, verbatim). 128-node
// buckets, 782 blocks x 512 threads. Zero global atomics.
// ---------------------------------------------------------------------------
__global__ __launch_bounds__(512) void bin3_kernel(
    const unsigned* __restrict__ queue, const int* __restrict__ qtail,
    int* __restrict__ cnt_out, int* __restrict__ row_start,
    int* __restrict__ sorted_src)
{
    __shared__ int cnt[128];
    __shared__ int ebase[128];
    __shared__ int run[128];
    __shared__ unsigned staged[QCAP_B];
    __shared__ int wpart[2];

    int tid = threadIdx.x;
    int b = blockIdx.x;
    int lane = tid & 63, wv = tid >> 6;

    if (tid < 128) { cnt[tid] = 0; run[tid] = 0; }
    __syncthreads();

    int n = min(qtail[b], QCAP_B);
    const unsigned* q = queue + (size_t)b * QCAP_B;

    for (int i = tid; i < n; i += 512) {
        unsigned e = q[i];
        staged[i] = e;
        atomicAdd(&cnt[e >> 17], 1);
    }
    __syncthreads();

    int inc = 0, v = 0;
    if (tid < 128) {
        v = cnt[tid];
        inc = v;
        for (int off = 1; off < 64; off <<= 1) {
            int t = __shfl_up(inc, off);
            if (lane >= off) inc += t;
        }
        if (lane == 63) wpart[wv] = inc;
    }
    __syncthreads();
    if (tid == 0) { int a = wpart[0]; wpart[0] = 0; wpart[1] = a; }
    __syncthreads();

    int gb = b * QCAP_B;
    if (tid < 128) {
        int eb = wpart[wv] + inc - v;
        ebase[tid] = eb;
        int node = b * 128 + tid;
        if (node < N_NODES) {
            cnt_out[node] = v;
            row_start[node] = gb + eb;
        }
    }
    __syncthreads();

    for (int i = tid; i < n; i += 512) {
        unsigned e = staged[i];
        int r = (int)(e >> 17);
        int k = atomicAdd(&run[r], 1);
        sorted_src[gb + ebase[r] + k] = (int)(e & 0x1FFFFu);
    }
}

// ---------------------------------------------------------------------------
// FUSED gather + 2-layer MFMA MLP, v2. The r2 failure is avoided by keeping
// the r1 gather geometry EXACTLY (8 nodes/wave, 4 waves, 32 nodes/block,
// 3125 blocks): gather accumulates per-node rows, writes bf16 rows to LDS
// (stride 72 u16 -> A-frag ds_read_b128 ~conflict-free), then the 4 waves
// split the MLP: wave w -> node-group gr=w&1 (16 rows), ct pair w>>1.
// Hidden layer round-trips through LDS (full 64 cols needed cross-wave).
// Replaces the xa global round-trip (25.6MB) + separate MLP dispatch; the
// kernel-boundary global barrier becomes two per-block __syncthreads.
// Layer 1 writes hb to a SEPARATE buffer (other blocks still gather xb).
// ---------------------------------------------------------------------------
#define XS 72   // u16 stride for LDS feature rows (144 B)

template <int WRITE_BF16>
__global__ __launch_bounds__(256) void gin_fused_kernel(
    const u16* __restrict__ xin, const int* __restrict__ cnt_arr,
    const int* __restrict__ row_start, const int* __restrict__ sorted_src,
    const u16* __restrict__ Wf, const float* __restrict__ b1,
    const float* __restrict__ b2, float* __restrict__ outf,
    u16* __restrict__ outb)
{
    __shared__ u16 xrow[32 * XS];   // 4608 B: gathered rows (bf16)
    __shared__ u16 hrow[32 * XS];   // 4608 B: hidden rows (bf16)

    int tid  = threadIdx.x;
    int lane = tid & 63;
    int w    = tid >> 6;
    int g    = lane >> 3;        // group (node within wave)
    int k    = lane & 7;         // 16B chunk within row / edge slot in batch
    int nbase = blockIdx.x * 32;
    int node  = nbase + w * 8 + g;   // 3125 blocks * 32 = 100000 exact

    // ================= phase 1: gather (r1 mechanics, verbatim) ===========
    int cnt  = cnt_arr[node];
    int base = row_start[node];

    const uint4 sv = *(const uint4*)(xin + ((size_t)node * D + k * 8));
    float accl[4], acch[4];
#pragma unroll
    for (int i = 0; i < 4; ++i) {
        unsigned d = ((const unsigned*)&sv)[i];
        unsigned lo = d << 16, hi = d & 0xFFFF0000u;
        __builtin_memcpy(&accl[i], &lo, 4);
        __builtin_memcpy(&acch[i], &hi, 4);
    }

    int mc = cnt;
    mc = max(mc, __shfl_xor(mc, 8));
    mc = max(mc, __shfl_xor(mc, 16));
    mc = max(mc, __shfl_xor(mc, 32));

    int lb4 = (lane & 56) << 2;  // byte addr of group's lane 0 for bpermute

    for (int c = 0; c < mc; c += 8) {
        int s = (c + k < cnt) ? sorted_src[base + c + k] : N_NODES;

        uint4 v[8];
#pragma unroll
        for (int j = 0; j < 8; ++j) {
            int idx = __builtin_amdgcn_ds_bpermute(lb4 + 4 * j, s);
            v[j] = *(const uint4*)(xin + (((size_t)(unsigned)idx) * D + (k << 3)));
        }
#pragma unroll
        for (int j = 0; j < 8; ++j) {
#pragma unroll
            for (int i = 0; i < 4; ++i) {
                unsigned d = ((const unsigned*)&v[j])[i];
                unsigned lo = d << 16, hi = d & 0xFFFF0000u;
                float fl, fh;
                __builtin_memcpy(&fl, &lo, 4);
                __builtin_memcpy(&fh, &hi, 4);
                accl[i] += fl;
                acch[i] += fh;
            }
        }
    }

    // pack to bf16 and store this lane's 16B into the block's LDS row tile
    {
        unsigned outp[4];
#pragma unroll
        for (int i = 0; i < 4; ++i)
            outp[i] = (unsigned)f2bf(accl[i]) | ((unsigned)f2bf(acch[i]) << 16);
        *(uint4*)&xrow[(w * 8 + g) * XS + k * 8] = *(const uint4*)outp;
    }
    __syncthreads();

    // ================= phase 2: MLP (wave w -> group gr, ct pair) ==========
    int quad = lane >> 4;
    int l16  = lane & 15;
    int gr   = w & 1;            // node group: rows gr*16 .. gr*16+15
    int ct0  = (w >> 1) * 2;     // this wave's two output-column tiles

    // ---- layer 1: u = relu(xrow @ W1 + b1) ----
    const u16* xp = &xrow[(gr * 16 + l16) * XS + quad * 8];
    bf16x8 a0 = *(const bf16x8*)xp;          // k = quad*8+j
    bf16x8 a1 = *(const bf16x8*)(xp + 32);   // k = 32+quad*8+j

    f32x4 acc[2];
#pragma unroll
    for (int cc = 0; cc < 2; ++cc) {
        int ct = ct0 + cc;
        float bv = b1[ct * 16 + l16];
        acc[cc] = (f32x4){bv, bv, bv, bv};
        bf16x8 bf0 = *(const bf16x8*)(Wf + (size_t)((0 * 4 + ct) * 2 + 0) * 512 + lane * 8);
        bf16x8 bf1 = *(const bf16x8*)(Wf + (size_t)((0 * 4 + ct) * 2 + 1) * 512 + lane * 8);
        acc[cc] = __builtin_amdgcn_mfma_f32_16x16x32_bf16(a0, bf0, acc[cc], 0, 0, 0);
        acc[cc] = __builtin_amdgcn_mfma_f32_16x16x32_bf16(a1, bf1, acc[cc], 0, 0, 0);
    }

    // relu -> bf16 -> LDS hidden rows (C-layout: row=quad*4+r, col=ct*16+l16)
#pragma unroll
    for (int cc = 0; cc < 2; ++cc)
#pragma unroll
        for (int r = 0; r < 4; ++r)
            hrow[(gr * 16 + quad * 4 + r) * XS + (ct0 + cc) * 16 + l16] =
                f2bf(fmaxf(acc[cc][r], 0.f));
    __syncthreads();

    // ---- layer 2: v = u @ W2 + b2 ----
    const u16* up = &hrow[(gr * 16 + l16) * XS + quad * 8];
    bf16x8 u0 = *(const bf16x8*)up;
    bf16x8 u1 = *(const bf16x8*)(up + 32);

#pragma unroll
    for (int cc = 0; cc < 2; ++cc) {
        int ct = ct0 + cc;
        float bv = b2[ct * 16 + l16];
        acc[cc] = (f32x4){bv, bv, bv, bv};
        bf16x8 bf0 = *(const bf16x8*)(Wf + (size_t)((1 * 4 + ct) * 2 + 0) * 512 + lane * 8);
        bf16x8 bf1 = *(const bf16x8*)(Wf + (size_t)((1 * 4 + ct) * 2 + 1) * 512 + lane * 8);
        acc[cc] = __builtin_amdgcn_mfma_f32_16x16x32_bf16(u0, bf0, acc[cc], 0, 0, 0);
        acc[cc] = __builtin_amdgcn_mfma_f32_16x16x32_bf16(u1, bf1, acc[cc], 0, 0, 0);
    }

    // epilogue (C-layout scatter; 16-lane groups write contiguous runs)
#pragma unroll
    for (int r = 0; r < 4; ++r) {
        int nd = nbase + gr * 16 + quad * 4 + r;
#pragma unroll
        for (int cc = 0; cc < 2; ++cc) {
            int ct = ct0 + cc;
            if (WRITE_BF16)
                outb[(size_t)nd * D + ct * 16 + l16] = f2bf(fmaxf(acc[cc][r], 0.f));
            else
                outf[(size_t)nd * D + ct * 16 + l16] = acc[cc][r];
        }
    }
}

extern "C" void kernel_launch(void* const* d_in, const int* in_sizes, int n_in,
                              void* d_out, int out_size, void* d_ws, size_t ws_size,
                              hipStream_t stream)
{
    const float* x  = (const float*)d_in[0];
    const int*   ei = (const int*)d_in[1];
    const float* W1 = (const float*)d_in[2];
    const float* b1 = (const float*)d_in[3];
    const float* W2 = (const float*)d_in[4];
    const float* b2 = (const float*)d_in[5];
    float* out = (float*)d_out;

    // workspace (~41.6 MB):
    //   qtail(1024) | cnt(100096) | row_start(100096)
    //   queue (782*2432 u32) | sorted_src (782*2432 int)
    //   Wf (8192 u16) | hb ((N+1) rows bf16) | xb ((N+1) rows bf16)
    int* qtail      = (int*)d_ws;
    int* cnt_arr    = qtail + 1024;
    int* row_start  = cnt_arr + 100096;
    unsigned* queue = (unsigned*)(row_start + 100096);
    int* sorted_src = (int*)(queue + (size_t)NBUCKET * QCAP_B);
    u16* Wf         = (u16*)(sorted_src + (size_t)NBUCKET * QCAP_B);
    u16* hb_b       = Wf + 8192;
    u16* xb_b       = hb_b + (size_t)(N_NODES + 1) * D;

    const int fused_blocks = (N_NODES + 31) / 32;   // 3125 (32 nodes/block)

    // ---- prep: misc (qtail, dummy rows, weights) then sort(+convert) ----
    misc_kernel<<<1, 256, 0, stream>>>(W1, W2, Wf, qtail, xb_b, hb_b);
    sort_kernel<<<SORT_BLOCKS, 1024, 0, stream>>>(ei, qtail, queue, x, xb_b);
    bin3_kernel<<<NBUCKET, 512, 0, stream>>>(queue, qtail, cnt_arr, row_start, sorted_src);

    // ---- layer 1: hb = relu(MLP(xb + gather(xb))) ----
    gin_fused_kernel<1><<<fused_blocks, 256, 0, stream>>>(
        xb_b, cnt_arr, row_start, sorted_src, Wf, b1, b2, nullptr, hb_b);

    // ---- layer 2: out = MLP(hb + gather(hb)) ----
    gin_fused_kernel<0><<<fused_blocks, 256, 0, stream>>>(
        hb_b, cnt_arr, row_start, sorted_src, Wf, b1, b2, out, nullptr);
}

// Round 13
// 181.282 us; speedup vs baseline: 1.1779x; 1.0140x over previous
//
#include <hip/hip_runtime.h>

#define N_NODES 100000
#define N_EDGES 1600000
#define D 64
#define NBUCKET 782              // ceil(N_NODES/128), bucket = 128 dst nodes
#define QCAP_B 2432              // per-bucket queue cap (mean ~2046, +8.5 sd)
#define EPB 4096                 // edges per sort block
#define SORT_BLOCKS 391          // ceil(N_EDGES/EPB)

typedef unsigned short u16;
typedef short bf16x8 __attribute__((ext_vector_type(8)));
typedef float f32x4  __attribute__((ext_vector_type(4)));

__device__ __forceinline__ u16 f2bf(float f) {
    unsigned u;
    __builtin_memcpy(&u, &f, 4);
    u = (u + 0x7FFFu + ((u >> 16) & 1u)) >> 16;
    return (u16)u;
}

// ---------------------------------------------------------------------------
// Tiny prep (1 block): qtail zero (must precede sort's atomics), dummy-row
// zero in BOTH feature buffers, W1/W2 -> bf16 MFMA B-fragment pack.
// frag f = (layer*4 + ct)*2 + kf holds B[k=kf*32+quad*8+j][n=ct*16+(lane&15)]
// at u16 offset f*512 + lane*8 + j.
// ---------------------------------------------------------------------------
__global__ __launch_bounds__(256) void misc_kernel(
    const float* __restrict__ W1, const float* __restrict__ W2,
    u16* __restrict__ Wf, int* __restrict__ qtail,
    u16* __restrict__ xb, u16* __restrict__ hb)
{
    int tid = threadIdx.x;
#pragma unroll
    for (int q = 0; q < 4; ++q)
        qtail[tid + q * 256] = 0;
    if (tid < 32) {
        ((unsigned*)(xb + (size_t)N_NODES * D))[tid] = 0;
        ((unsigned*)(hb + (size_t)N_NODES * D))[tid] = 0;
    }
#pragma unroll
    for (int t = tid; t < 16 * 64; t += 256) {
        int f = t >> 6, lane = t & 63;
        int layer = f >> 3, ct = (f >> 1) & 3, kf = f & 1;
        const float* W = layer ? W2 : W1;
        int col = ct * 16 + (lane & 15);
        int krow = kf * 32 + (lane >> 4) * 8;
        u16* o = Wf + f * 512 + lane * 8;
#pragma unroll
        for (int j = 0; j < 8; ++j)
            o[j] = f2bf(W[(krow + j) * D + col]);
    }
}

// ---------------------------------------------------------------------------
// Block-level counting sort of 4096 edges into 782 bucket queues (r11/r12,
// verbatim). 1024 threads, 16-wave shfl scan, register-staged ei, fused
// x->bf16 convert. Entry packs (dst&127)<<17 | src.
// ---------------------------------------------------------------------------
__global__ __launch_bounds__(1024) void sort_kernel(
    const int* __restrict__ ei, int* __restrict__ qtail,
    unsigned* __restrict__ queue, const float* __restrict__ x,
    u16* __restrict__ xb)
{
    __shared__ int cnt[1024];
    __shared__ int base_s[1024];
    __shared__ int gbase[1024];
    __shared__ int run[1024];
    __shared__ unsigned staged[EPB];
    __shared__ int gposa[EPB];
    __shared__ int wpart[16];
    __shared__ int tot_s;

    int tid = threadIdx.x;
    int e0 = blockIdx.x * EPB;
    int lane = tid & 63, wv = tid >> 6;

    cnt[tid] = 0; run[tid] = 0;

    // ---- fused convert slice: x (f32) -> xb (bf16), ~4 float4/thread ----
    for (int i = blockIdx.x * 1024 + tid; i < N_NODES * D / 4;
         i += SORT_BLOCKS * 1024) {
        float4 v = ((const float4*)x)[i];
        ushort4 o;
        o.x = f2bf(v.x); o.y = f2bf(v.y); o.z = f2bf(v.z); o.w = f2bf(v.w);
        ((ushort4*)xb)[i] = o;
    }

    // ---- register-stage this thread's 4 edges + hist ----
    int limit = min(EPB, N_EDGES - e0);   // 4096 or 2560 (both %4 == 0)
    int g0 = 4 * tid;
    bool have = g0 < limit;
    uint4 src4, dst4;
    __syncthreads();   // cnt/run zero visible
    if (have) {
        src4 = *(const uint4*)(ei + e0 + g0);
        dst4 = *(const uint4*)(ei + N_EDGES + e0 + g0);
        atomicAdd(&cnt[((int)dst4.x) >> 7], 1);
        atomicAdd(&cnt[((int)dst4.y) >> 7], 1);
        atomicAdd(&cnt[((int)dst4.z) >> 7], 1);
        atomicAdd(&cnt[((int)dst4.w) >> 7], 1);
    }
    __syncthreads();

    // ---- 1024-wide exclusive scan: 16 waves shfl-scan 64 each + combine ----
    int v = cnt[tid];
    int inc = v;
    for (int off = 1; off < 64; off <<= 1) {
        int t = __shfl_up(inc, off);
        if (lane >= off) inc += t;
    }
    if (lane == 63) wpart[wv] = inc;
    __syncthreads();
    if (tid < 64) {
        int p = (lane < 16) ? wpart[lane] : 0;
        int ps = p;
        for (int off = 1; off < 16; off <<= 1) {
            int t = __shfl_up(ps, off);
            if (lane >= off) ps += t;
        }
        if (lane < 16) wpart[lane] = ps - p;   // exclusive wave base
    }
    __syncthreads();
    base_s[tid] = wpart[wv] + inc - v;         // exclusive prefix
    if (tid == 1023) tot_s = wpart[15] + inc;
    // ---- reserve global queue space (one atomic per nonempty bucket) ----
    if (tid < NBUCKET && cnt[tid] > 0)
        gbase[tid] = atomicAdd(&qtail[tid], cnt[tid]);
    __syncthreads();

    // ---- scatter into bucket-sorted LDS staging (from registers) ----
    if (have) {
        int ss[4] = {(int)src4.x, (int)src4.y, (int)src4.z, (int)src4.w};
        int dd[4] = {(int)dst4.x, (int)dst4.y, (int)dst4.z, (int)dst4.w};
#pragma unroll
        for (int q = 0; q < 4; ++q) {
            int b = dd[q] >> 7;
            int r = atomicAdd(&run[b], 1);
            int slot = base_s[b] + r;
            staged[slot] = ((unsigned)(dd[q] & 127) << 17) | (unsigned)ss[q];
            int gp = gbase[b] + r;
            gposa[slot] = (gp < QCAP_B) ? b * QCAP_B + gp : -1;
        }
    }
    __syncthreads();

    // ---- copy out (bucket-contiguous runs): 4 iters ----
    int total = tot_s;
    for (int i = tid; i < total; i += 1024) {
        int gp = gposa[i];
        if (gp >= 0) queue[gp] = staged[i];
    }
}

// ---------------------------------------------------------------------------
// Per-bucket LDS counting sort -> exact CSR (r11, verbatim). 128-node
// buckets, 782 blocks x 512 threads. Zero global atomics.
// ---------------------------------------------------------------------------
__global__ __launch_bounds__(512) void bin3_kernel(
    const unsigned* __restrict__ queue, const int* __restrict__ qtail,
    int* __restrict__ cnt_out, int* __restrict__ row_start,
    int* __restrict__ sorted_src)
{
    __shared__ int cnt[128];
    __shared__ int ebase[128];
    __shared__ int run[128];
    __shared__ unsigned staged[QCAP_B];
    __shared__ int wpart[2];

    int tid = threadIdx.x;
    int b = blockIdx.x;
    int lane = tid & 63, wv = tid >> 6;

    if (tid < 128) { cnt[tid] = 0; run[tid] = 0; }
    __syncthreads();

    int n = min(qtail[b], QCAP_B);
    const unsigned* q = queue + (size_t)b * QCAP_B;

    for (int i = tid; i < n; i += 512) {
        unsigned e = q[i];
        staged[i] = e;
        atomicAdd(&cnt[e >> 17], 1);
    }
    __syncthreads();

    int inc = 0, v = 0;
    if (tid < 128) {
        v = cnt[tid];
        inc = v;
        for (int off = 1; off < 64; off <<= 1) {
            int t = __shfl_up(inc, off);
            if (lane >= off) inc += t;
        }
        if (lane == 63) wpart[wv] = inc;
    }
    __syncthreads();
    if (tid == 0) { int a = wpart[0]; wpart[0] = 0; wpart[1] = a; }
    __syncthreads();

    int gb = b * QCAP_B;
    if (tid < 128) {
        int eb = wpart[wv] + inc - v;
        ebase[tid] = eb;
        int node = b * 128 + tid;
        if (node < N_NODES) {
            cnt_out[node] = v;
            row_start[node] = gb + eb;
        }
    }
    __syncthreads();

    for (int i = tid; i < n; i += 512) {
        unsigned e = staged[i];
        int r = (int)(e >> 17);
        int k = atomicAdd(&run[r], 1);
        sorted_src[gb + ebase[r] + k] = (int)(e & 0x1FFFFu);
    }
}

// ---------------------------------------------------------------------------
// FUSED gather + 2-layer MFMA MLP, v3 = r12 + within-block degree-balanced
// wave assignment. The block still owns 32 CONSECUTIVE nodes (self-rows,
// outputs, CSR segments keep r1 locality); a 32-element LDS rank-sort
// assigns similar-degree nodes to each wave's 8 slots, cutting the per-wave
// max-degree padding (~1.5x -> ~1.15x gather slots). LDS feature rows are
// indexed by NODE OFFSET, so the MLP phase is permutation-agnostic.
// ---------------------------------------------------------------------------
#define XS 72   // u16 stride for LDS feature rows (144 B)

template <int WRITE_BF16>
__global__ __launch_bounds__(256) void gin_fused_kernel(
    const u16* __restrict__ xin, const int* __restrict__ cnt_arr,
    const int* __restrict__ row_start, const int* __restrict__ sorted_src,
    const u16* __restrict__ Wf, const float* __restrict__ b1,
    const float* __restrict__ b2, float* __restrict__ outf,
    u16* __restrict__ outb)
{
    __shared__ u16 xrow[32 * XS];   // 4608 B: gathered rows (bf16), by node off
    __shared__ u16 hrow[32 * XS];   // 4608 B: hidden rows (bf16), by node off
    __shared__ int sdeg[32];
    __shared__ unsigned char sperm[32];   // slot -> node offset, deg-ranked

    int tid  = threadIdx.x;
    int lane = tid & 63;
    int w    = tid >> 6;
    int g    = lane >> 3;        // group slot within wave
    int k    = lane & 7;         // 16B chunk within row / edge slot in batch
    int nbase = blockIdx.x * 32; // 3125 blocks * 32 = 100000 exact

    // ---- phase 0: degree-rank the block's 32 nodes ----
    if (tid < 32) sdeg[tid] = cnt_arr[nbase + tid];
    __syncthreads();
    if (tid < 32) {
        int myd = sdeg[tid];
        int rank = 0;
#pragma unroll
        for (int j = 0; j < 32; ++j) {
            int dj = sdeg[j];
            rank += (dj > myd) || (dj == myd && j < tid);
        }
        sperm[rank] = (unsigned char)tid;   // rank 0 = highest degree
    }
    __syncthreads();

    int noff = sperm[w * 8 + g];            // this slot's node offset
    int node = nbase + noff;

    // ================= phase 1: gather (r1 mechanics) =====================
    int cnt  = cnt_arr[node];
    int base = row_start[node];

    const uint4 sv = *(const uint4*)(xin + ((size_t)node * D + k * 8));
    float accl[4], acch[4];
#pragma unroll
    for (int i = 0; i < 4; ++i) {
        unsigned d = ((const unsigned*)&sv)[i];
        unsigned lo = d << 16, hi = d & 0xFFFF0000u;
        __builtin_memcpy(&accl[i], &lo, 4);
        __builtin_memcpy(&acch[i], &hi, 4);
    }

    // wave max degree across the 8 slots (similar degrees -> tight bound)
    int mc = cnt;
    mc = max(mc, __shfl_xor(mc, 8));
    mc = max(mc, __shfl_xor(mc, 16));
    mc = max(mc, __shfl_xor(mc, 32));

    int lb4 = (lane & 56) << 2;  // byte addr of group's lane 0 for bpermute

    for (int c = 0; c < mc; c += 8) {
        int s = (c + k < cnt) ? sorted_src[base + c + k] : N_NODES;

        uint4 v[8];
#pragma unroll
        for (int j = 0; j < 8; ++j) {
            int idx = __builtin_amdgcn_ds_bpermute(lb4 + 4 * j, s);
            v[j] = *(const uint4*)(xin + (((size_t)(unsigned)idx) * D + (k << 3)));
        }
#pragma unroll
        for (int j = 0; j < 8; ++j) {
#pragma unroll
            for (int i = 0; i < 4; ++i) {
                unsigned d = ((const unsigned*)&v[j])[i];
                unsigned lo = d << 16, hi = d & 0xFFFF0000u;
                float fl, fh;
                __builtin_memcpy(&fl, &lo, 4);
                __builtin_memcpy(&fh, &hi, 4);
                accl[i] += fl;
                acch[i] += fh;
            }
        }
    }

    // pack to bf16, store at the node's own LDS row (permutation-agnostic)
    {
        unsigned outp[4];
#pragma unroll
        for (int i = 0; i < 4; ++i)
            outp[i] = (unsigned)f2bf(accl[i]) | ((unsigned)f2bf(acch[i]) << 16);
        *(uint4*)&xrow[noff * XS + k * 8] = *(const uint4*)outp;
    }
    __syncthreads();

    // ================= phase 2: MLP (wave w -> group gr, ct pair) ==========
    int quad = lane >> 4;
    int l16  = lane & 15;
    int gr   = w & 1;            // node group: rows gr*16 .. gr*16+15
    int ct0  = (w >> 1) * 2;     // this wave's two output-column tiles

    // ---- layer 1: u = relu(xrow @ W1 + b1) ----
    const u16* xp = &xrow[(gr * 16 + l16) * XS + quad * 8];
    bf16x8 a0 = *(const bf16x8*)xp;          // k = quad*8+j
    bf16x8 a1 = *(const bf16x8*)(xp + 32);   // k = 32+quad*8+j

    f32x4 acc[2];
#pragma unroll
    for (int cc = 0; cc < 2; ++cc) {
        int ct = ct0 + cc;
        float bv = b1[ct * 16 + l16];
        acc[cc] = (f32x4){bv, bv, bv, bv};
        bf16x8 bf0 = *(const bf16x8*)(Wf + (size_t)((0 * 4 + ct) * 2 + 0) * 512 + lane * 8);
        bf16x8 bf1 = *(const bf16x8*)(Wf + (size_t)((0 * 4 + ct) * 2 + 1) * 512 + lane * 8);
        acc[cc] = __builtin_amdgcn_mfma_f32_16x16x32_bf16(a0, bf0, acc[cc], 0, 0, 0);
        acc[cc] = __builtin_amdgcn_mfma_f32_16x16x32_bf16(a1, bf1, acc[cc], 0, 0, 0);
    }

    // relu -> bf16 -> LDS hidden rows (C-layout: row=quad*4+r, col=ct*16+l16)
#pragma unroll
    for (int cc = 0; cc < 2; ++cc)
#pragma unroll
        for (int r = 0; r < 4; ++r)
            hrow[(gr * 16 + quad * 4 + r) * XS + (ct0 + cc) * 16 + l16] =
                f2bf(fmaxf(acc[cc][r], 0.f));
    __syncthreads();

    // ---- layer 2: v = u @ W2 + b2 ----
    const u16* up = &hrow[(gr * 16 + l16) * XS + quad * 8];
    bf16x8 u0 = *(const bf16x8*)up;
    bf16x8 u1 = *(const bf16x8*)(up + 32);

#pragma unroll
    for (int cc = 0; cc < 2; ++cc) {
        int ct = ct0 + cc;
        float bv = b2[ct * 16 + l16];
        acc[cc] = (f32x4){bv, bv, bv, bv};
        bf16x8 bf0 = *(const bf16x8*)(Wf + (size_t)((1 * 4 + ct) * 2 + 0) * 512 + lane * 8);
        bf16x8 bf1 = *(const bf16x8*)(Wf + (size_t)((1 * 4 + ct) * 2 + 1) * 512 + lane * 8);
        acc[cc] = __builtin_amdgcn_mfma_f32_16x16x32_bf16(u0, bf0, acc[cc], 0, 0, 0);
        acc[cc] = __builtin_amdgcn_mfma_f32_16x16x32_bf16(u1, bf1, acc[cc], 0, 0, 0);
    }

    // epilogue (C-layout scatter; 16-lane groups write contiguous runs)
#pragma unroll
    for (int r = 0; r < 4; ++r) {
        int nd = nbase + gr * 16 + quad * 4 + r;
#pragma unroll
        for (int cc = 0; cc < 2; ++cc) {
            int ct = ct0 + cc;
            if (WRITE_BF16)
                outb[(size_t)nd * D + ct * 16 + l16] = f2bf(fmaxf(acc[cc][r], 0.f));
            else
                outf[(size_t)nd * D + ct * 16 + l16] = acc[cc][r];
        }
    }
}

extern "C" void kernel_launch(void* const* d_in, const int* in_sizes, int n_in,
                              void* d_out, int out_size, void* d_ws, size_t ws_size,
                              hipStream_t stream)
{
    const float* x  = (const float*)d_in[0];
    const int*   ei = (const int*)d_in[1];
    const float* W1 = (const float*)d_in[2];
    const float* b1 = (const float*)d_in[3];
    const float* W2 = (const float*)d_in[4];
    const float* b2 = (const float*)d_in[5];
    float* out = (float*)d_out;

    // workspace (~41.6 MB):
    //   qtail(1024) | cnt(100096) | row_start(100096)
    //   queue (782*2432 u32) | sorted_src (782*2432 int)
    //   Wf (8192 u16) | hb ((N+1) rows bf16) | xb ((N+1) rows bf16)
    int* qtail      = (int*)d_ws;
    int* cnt_arr    = qtail + 1024;
    int* row_start  = cnt_arr + 100096;
    unsigned* queue = (unsigned*)(row_start + 100096);
    int* sorted_src = (int*)(queue + (size_t)NBUCKET * QCAP_B);
    u16* Wf         = (u16*)(sorted_src + (size_t)NBUCKET * QCAP_B);
    u16* hb_b       = Wf + 8192;
    u16* xb_b       = hb_b + (size_t)(N_NODES + 1) * D;

    const int fused_blocks = (N_NODES + 31) / 32;   // 3125 (32 nodes/block)

    // ---- prep: misc (qtail, dummy rows, weights) then sort(+convert) ----
    misc_kernel<<<1, 256, 0, stream>>>(W1, W2, Wf, qtail, xb_b, hb_b);
    sort_kernel<<<SORT_BLOCKS, 1024, 0, stream>>>(ei, qtail, queue, x, xb_b);
    bin3_kernel<<<NBUCKET, 512, 0, stream>>>(queue, qtail, cnt_arr, row_start, sorted_src);

    // ---- layer 1: hb = relu(MLP(xb + gather(xb))) ----
    gin_fused_kernel<1><<<fused_blocks, 256, 0, stream>>>(
        xb_b, cnt_arr, row_start, sorted_src, Wf, b1, b2, nullptr, hb_b);

    // ---- layer 2: out = MLP(hb + gather(hb)) ----
    gin_fused_kernel<0><<<fused_blocks, 256, 0, stream>>>(
        hb_b, cnt_arr, row_start, sorted_src, Wf, b1, b2, out, nullptr);
}